// Round 10
// baseline (358.346 us; speedup 1.0000x reference)
//
#include <hip/hip_runtime.h>
#include <hip/hip_bf16.h>
#include <cstdint>

typedef __attribute__((ext_vector_type(8))) __bf16 bf16x8;
typedef __attribute__((ext_vector_type(4))) __bf16 bf16x4;
typedef __attribute__((ext_vector_type(4))) float  f32x4;

#define N_IMG 3136   // 56*56
#define NB16  196    // 3136/16
#define CB8   56     // 448/8
#define P_CNT 2496   // 52*48 interior pixels
#define NDIR  34     // stencil directions

// stencil offsets dy*56+dx for RADIUS=5 (matches get_indices_of_pairs order)
__constant__ int c_offs[NDIR] = {
  1,2,3,4,
  52,53,54,55,56,57,58,59,60,
  108,109,110,111,112,113,114,115,116,
  165,166,167,168,169,170,171,
  222,223,224,225,226};

__device__ __forceinline__ void block_sync(){
  // raw barrier: LDS drained, vector-mem loads stay in flight across it
  asm volatile("s_waitcnt lgkmcnt(0)\n\ts_barrier" ::: "memory");
}

__device__ __forceinline__ float elu_f(float v){
  return v > 0.f ? v : expm1f(v);
}

// ---------------- weight f32->bf16 prep (one launch, 4 segments) -------------
__global__ __launch_bounds__(256) void cvt_weights(
    const float* __restrict__ w83, const float* __restrict__ w84,
    const float* __restrict__ w85, const float* __restrict__ w9,
    __bf16* __restrict__ o83, __bf16* __restrict__ o84,
    __bf16* __restrict__ o85, __bf16* __restrict__ o9)
{
  int i = blockIdx.x*256 + threadIdx.x;  // index in float4 units
  const float* src; __bf16* dst; int off;
  if      (i <   8192){ src=w83; dst=o83; off=i; }
  else if (i <  40960){ src=w84; dst=o84; off=i-8192; }
  else if (i < 303104){ src=w85; dst=o85; off=i-40960; }
  else if (i < 353280){ src=w9 ; dst=o9 ; off=i-303104; }
  else return;
  f32x4 v = ((const f32x4*)src)[off];
  bf16x4 o;
  o[0]=(__bf16)v[0]; o[1]=(__bf16)v[1]; o[2]=(__bf16)v[2]; o[3]=(__bf16)v[3];
  ((bf16x4*)dst)[off] = o;
}

// ---------------- Xt prep: transpose+cvt conv -> B-granule layout -------------
// X[b][k][n] f32  ->  Xt element (k,n) of slab kb=k/64 stored at
//   ((b*NSLAB+kb)*3136 + n)*64 + ((g ^ (n&7))<<3) + (k&7),  g=(k>>3)&7
// so each GEMM tile (64 n, 64 k) is one CONTIGUOUS 8KB block, pre-swizzled.
// Reads are row-contiguous (1KB per 64-lane instr); writes 128B/row n.
template<int KTOT>
__device__ __forceinline__ void xt_body(
    const float* __restrict__ X, __bf16* __restrict__ Xt, int bidx,
    __bf16* T /* [784][68] */)
{
  constexpr int NSLAB = KTOT/64;
  const int b = bidx / NSLAB, kb = bidx % NSLAB;
  const float* src = X + ((size_t)b*KTOT + kb*64)*N_IMG;
  __bf16* dst = Xt + (size_t)bidx * N_IMG * 64;
  const int tid = threadIdx.x, lane = tid & 63, w = tid >> 6;

  for (int c = 0; c < 4; ++c){
    const int n0 = c*784;
    // ---- load 64 rows x 784 cols (contiguous per row), transpose into LDS --
    #pragma unroll
    for (int i = 0; i < 8; ++i){
      const int r = w*8 + i;                 // k-row within slab
      const float* rp = src + (size_t)r*N_IMG + n0;
      const int g = r >> 3, rb = r & 7;
      #pragma unroll
      for (int j = 0; j < 4; ++j){
        const int idx = j*64 + lane;         // f32x4 index in row-chunk (196)
        if (idx < 196){
          f32x4 v = *(const f32x4*)(rp + idx*4);
          #pragma unroll
          for (int e = 0; e < 4; ++e){
            const int n = idx*4 + e;
            T[n*68 + ((g ^ (n & 7)) << 3) + rb] = (__bf16)v[e];
          }
        }
      }
    }
    block_sync();
    // ---- write out: 784 rows x 128B contiguous (swizzle already in LDS) ----
    for (int n = tid; n < 784; n += 512){
      const __bf16* lr = &T[n*68];
      __bf16* gr = dst + (size_t)(n0 + n)*64;
      #pragma unroll
      for (int q = 0; q < 8; ++q){
        *(uint4*)(gr + q*8) = *(const uint4*)(lr + q*8);
      }
    }
    block_sync();   // T reused next chunk
  }
}

__global__ __launch_bounds__(512) void xt_prep(
    const float* __restrict__ c4, const float* __restrict__ c5,
    const float* __restrict__ c6,
    __bf16* __restrict__ xt4, __bf16* __restrict__ xt5, __bf16* __restrict__ xt6)
{
  __shared__ __bf16 T[784*68];
  const int gid = blockIdx.x;
  if (gid < 256)      xt_body<4096>(c6, xt6, gid,     T);   // 4b x 64 slabs
  else if (gid < 320) xt_body<1024>(c5, xt5, gid-256, T);   // 4b x 16
  else                xt_body< 512>(c4, xt4, gid-320, T);   // 4b x 8
}

// ---------------- fused feature GEMMs -----------------------------------------
// y1[n,c] = elu(W[MT x KTOT] * Xt) for three segments in ONE dispatch:
//   blocks [0,196)   : Xt6 * w85 (MT=256, K=4096, MI=2)   <- long pole, first
//   blocks [196,392) : Xt5 * w84 (MT=128, K=1024, MI=1)
//   blocks [392,588) : Xt4 * w83 (MT=64,  K=512,  MI=1, 4 compute waves)
// Per step the whole B tile is ONE contiguous 8KB read (Xt layout), reg-staged
// to a single 8KB LDS buffer: 1 dwordx4 load + 1 ds_write_b128 per thread.
// Two raw barriers/phase, every wait a counted vmcnt (never 0 in main loop).
// A (weights) frag-loaded direct from global/L2, 2 sets, load-after-use.
// Output in MFMA-B-fragment layout: idx=(((b*196+n/16)*56+c/8)*16+n%16)*8+c%8
template<int MT, int KTOT, int MWA>
__device__ __forceinline__ void feat_body(
    const __bf16* __restrict__ Xt, const __bf16* __restrict__ Wb,
    __bf16* __restrict__ y1, int c_off, int bidx, __bf16* Bl)
{
  constexpr int MI    = MT/(MWA*16);     // m-frags per compute wave (1 or 2)
  constexpr int NI    = 4;               // n-frags per wave (all 64 n)
  constexpr int NSTEP = KTOT/64;
  static_assert(MI==1 || MI==2, "");
  static_assert(NSTEP % 2 == 0, "");
  constexpr size_t TSTRIDE = (size_t)N_IMG*64;   // elems between k-slabs

  const int tid  = threadIdx.x;          // 0..511
  const int lane = tid & 63;
  const int wm   = tid >> 6;             // 0..7
  const int l15  = lane & 15;
  const int l4   = lane >> 4;
  const int b    = bidx / 49;
  const int n0   = (bidx % 49) * 64;
  const __bf16* srcb = Xt + ((size_t)b*NSTEP*N_IMG + (size_t)n0)*64 + tid*8;

  bf16x8 a0[MI*2], a1[MI*2];
  f32x4 acc[MI][NI];
  const f32x4 fz = {0.f,0.f,0.f,0.f};
  #pragma unroll
  for (int mi=0; mi<MI; ++mi)
    #pragma unroll
    for (int ni=0; ni<NI; ++ni) acc[mi][ni] = fz;

#define LOADA(ar, t) { \
  if (wm < MWA && (t) < NSTEP) { \
    _Pragma("unroll") \
    for (int _mi=0;_mi<MI;++_mi) \
      _Pragma("unroll") \
      for (int _kk=0;_kk<2;++_kk) \
        (ar)[_mi*2+_kk] = *(const bf16x8*)(Wb + (size_t)(wm*(MI*16)+_mi*16+l15)*KTOT + (t)*64 + _kk*32 + l4*8); \
  } }

#define MFMAS(ar) { \
  if (wm < MWA) { \
    _Pragma("unroll") \
    for (int _kk=0;_kk<2;++_kk) \
      _Pragma("unroll") \
      for (int _ni=0;_ni<NI;++_ni){ \
        const int _n = _ni*16 + l15; \
        bf16x8 _bv = *(const bf16x8*)&Bl[_n*64 + (((_kk*4+l4) ^ (_n & 7))<<3)]; \
        _Pragma("unroll") \
        for (int _mi=0;_mi<MI;++_mi) \
          acc[_mi][_ni] = __builtin_amdgcn_mfma_f32_16x16x32_bf16((ar)[_mi*2+_kk], _bv, acc[_mi][_ni], 0,0,0); \
      } \
  } }

  // prologue: 2 B tiles + 2 A steps in flight
  uint4 g0 = *(const uint4*)(srcb);
  uint4 g1 = *(const uint4*)(srcb + TSTRIDE);
  LOADA(a0, 0);
  LOADA(a1, 1);
  for (int s=0; s<NSTEP; s+=2){
    // even phase: tile s
    *(uint4*)&Bl[tid*8] = g0;            // ds_write_b128 (counted vmcnt wait on g0)
    if (s+2 < NSTEP) g0 = *(const uint4*)(srcb + (size_t)(s+2)*TSTRIDE);
    block_sync();                         // tile visible to all waves
    MFMAS(a0);
    LOADA(a0, s+2);
    __builtin_amdgcn_sched_barrier(0);
    asm volatile("s_barrier" ::: "memory");   // all reads done before next write
    // odd phase: tile s+1
    *(uint4*)&Bl[tid*8] = g1;
    if (s+3 < NSTEP) g1 = *(const uint4*)(srcb + (size_t)(s+3)*TSTRIDE);
    block_sync();
    MFMAS(a1);
    LOADA(a1, s+3);
    __builtin_amdgcn_sched_barrier(0);
    asm volatile("s_barrier" ::: "memory");
  }
#undef LOADA
#undef MFMAS

  // ---- epilogue: elu + store to fragment layout ----
  if (wm < MWA){
    #pragma unroll
    for (int mi=0; mi<MI; ++mi){
      const int c0 = c_off + wm*(MI*16) + mi*16 + l4*4;  // 4 consecutive channels
      const int cb = c0 >> 3;
      const int jj = c0 & 7;
      #pragma unroll
      for (int ni=0; ni<NI; ++ni){
        const int n = n0 + ni*16 + l15;
        size_t idx = ((((size_t)b*NB16 + (n>>4))*CB8 + cb)*16 + (n&15))*8 + jj;
        f32x4 a = acc[mi][ni];
        bf16x4 o;
        #pragma unroll
        for (int r=0;r<4;++r) o[r] = (__bf16)elu_f(a[r]);
        *(bf16x4*)(y1 + idx) = o;
      }
    }
  }
}

__global__ __launch_bounds__(512) void gemm_feat_fused(
    const __bf16* __restrict__ xt4, const __bf16* __restrict__ xt5,
    const __bf16* __restrict__ xt6,
    const __bf16* __restrict__ w83b, const __bf16* __restrict__ w84b,
    const __bf16* __restrict__ w85b, __bf16* __restrict__ y1)
{
  __shared__ __bf16 Bl[64*64];           // single 8KB staging buffer
  const int gid = blockIdx.x;
  if (gid < 196)       feat_body<256, 4096, 8>(xt6, w85b, y1, 192, gid,     Bl);
  else if (gid < 392)  feat_body<128, 1024, 8>(xt5, w84b, y1,  64, gid-196, Bl);
  else                 feat_body< 64,  512, 4>(xt4, w83b, y1,   0, gid-392, Bl);
}

// ---------------- output GEMM: x2[n, o] = elu(w9[448x448] * y1) -------------
// LDS-free, barrier-free: both operands frag-loaded direct (L2/L3-resident).
__global__ __launch_bounds__(256) void gemm_out(
    const __bf16* __restrict__ y1, const __bf16* __restrict__ w9b,
    __bf16* __restrict__ x2)
{
  const int nt = blockIdx.x, mt = blockIdx.y, b = blockIdx.z;
  const int tid = threadIdx.x;
  if (mt == 7){
    // zero the pad columns 448..511 of this n-tile
    const int row = tid >> 2, q = tid & 3;
    __bf16* p = x2 + ((size_t)b*N_IMG + nt*64 + row)*512 + 448 + q*16;
    uint4 z = {0u,0u,0u,0u};
    *(uint4*)p = z;
    *(uint4*)(p+8) = z;
    return;
  }
  const int lane = tid & 63, wid = tid >> 6;
  const int l15 = lane & 15, l4 = lane >> 4;
  // each wave owns one 16-col block of y1's fragment layout
  const __bf16* Bbase = y1 + ((size_t)b*NB16 + nt*4 + wid)*CB8*128;
  const __bf16* Abase = w9b + (size_t)(mt*64 + l15)*448 + l4*8;
  f32x4 acc[4];
  const f32x4 fz = {0.f,0.f,0.f,0.f};
  #pragma unroll
  for (int mi=0;mi<4;++mi) acc[mi] = fz;

  for (int s=0;s<7;++s){
    #pragma unroll
    for (int kk=0;kk<2;++kk){
      bf16x8 bv = *(const bf16x8*)(Bbase + (s*2+kk)*512 + lane*8);  // linear lane*16B
      #pragma unroll
      for (int mi=0;mi<4;++mi){
        bf16x8 av = *(const bf16x8*)(Abase + (size_t)mi*16*448 + s*64 + kk*32);
        acc[mi] = __builtin_amdgcn_mfma_f32_16x16x32_bf16(av, bv, acc[mi], 0,0,0);
      }
    }
  }
  #pragma unroll
  for (int mi=0;mi<4;++mi){
    const int o = mt*64 + mi*16 + l4*4;
    const int n = nt*64 + wid*16 + l15;
    f32x4 a = acc[mi];
    bf16x4 v;
    #pragma unroll
    for (int r=0;r<4;++r) v[r] = (__bf16)elu_f(a[r]);
    *(bf16x4*)(x2 + ((size_t)b*N_IMG + n)*512 + o) = v;
  }
}

// ---------------- affinity stencil: one wave per (b, p) ---------------------
__global__ __launch_bounds__(256) void affinity_kernel(
    const __bf16* __restrict__ x2, float* __restrict__ out)
{
  const int b = blockIdx.x;                 // b fastest -> each XCD sees one batch
  const int lane = threadIdx.x & 63, wid = threadIdx.x >> 6;
  const int p = blockIdx.y*4 + wid;
  const int from = (p/48)*56 + 4 + (p%48);
  const __bf16* xb = x2 + (size_t)b*N_IMG*512;
  bf16x8 ffv = *(const bf16x8*)(xb + (size_t)from*512 + lane*8);
  float ff[8];
  #pragma unroll
  for (int j=0;j<8;++j) ff[j] = (float)ffv[j];
  for (int d=0; d<NDIR; ++d){
    const int to = from + c_offs[d];
    bf16x8 ftv = *(const bf16x8*)(xb + (size_t)to*512 + lane*8);
    float s = 0.f;
    #pragma unroll
    for (int j=0;j<8;++j) s += fabsf(ff[j] - (float)ftv[j]);
    #pragma unroll
    for (int m=1;m<64;m<<=1) s += __shfl_xor(s, m, 64);
    if (lane == 0) out[((size_t)b*NDIR + d)*P_CNT + p] = expf(-s*(1.f/448.f));
  }
}

extern "C" void kernel_launch(void* const* d_in, const int* in_sizes, int n_in,
                              void* d_out, int out_size, void* d_ws, size_t ws_size,
                              hipStream_t stream)
{
  (void)in_sizes; (void)n_in; (void)out_size; (void)ws_size;
  const float* conv4 = (const float*)d_in[0];
  const float* conv5 = (const float*)d_in[1];
  const float* conv6 = (const float*)d_in[2];
  const float* w83   = (const float*)d_in[3];
  const float* w84   = (const float*)d_in[4];
  const float* w85   = (const float*)d_in[5];
  const float* w9    = (const float*)d_in[6];
  // ind_from / ind_to (d_in[7], d_in[8]) are recomputed on device (hardcoded stencil)
  float* out = (float*)d_out;
  char* ws = (char*)d_ws;
  // workspace layout (168,206,336 bytes total)
  __bf16* w83b = (__bf16*)(ws + 0);          //  64x512
  __bf16* w84b = (__bf16*)(ws + 65536);      // 128x1024
  __bf16* w85b = (__bf16*)(ws + 327680);     // 256x4096
  __bf16* w9b  = (__bf16*)(ws + 2424832);    // 448x448
  __bf16* y1   = (__bf16*)(ws + 2826240);    // 4*3136*448, fragment layout
  __bf16* x2   = (__bf16*)(ws + 14065664);   // 4*3136*512 (448 + zero pad)
  __bf16* xt6  = (__bf16*)(ws + 26910720);   // 4b x 64 slabs x 3136 x 128B
  __bf16* xt5  = (__bf16*)(ws + 129671168);  // 4b x 16 slabs
  __bf16* xt4  = (__bf16*)(ws + 155361280);  // 4b x  8 slabs

  cvt_weights<<<1380, 256, 0, stream>>>(w83,w84,w85,w9, w83b,w84b,w85b,w9b);
  xt_prep<<<352, 512, 0, stream>>>(conv4, conv5, conv6, xt4, xt5, xt6);
  // fused g3+g2+g1: blocks [0,196)=conv6, [196,392)=conv5, [392,588)=conv4
  gemm_feat_fused<<<588, 512, 0, stream>>>(xt4, xt5, xt6, w83b, w84b, w85b, y1);
  gemm_out<<<dim3(49,8,4), 256, 0, stream>>>(y1, w9b, x2);
  affinity_kernel<<<dim3(4,624), 256, 0, stream>>>(x2, out);
}

// Round 11
// 243.776 us; speedup vs baseline: 1.4700x; 1.4700x over previous
//
#include <hip/hip_runtime.h>
#include <hip/hip_bf16.h>
#include <cstdint>

typedef __attribute__((ext_vector_type(8))) __bf16 bf16x8;
typedef __attribute__((ext_vector_type(4))) __bf16 bf16x4;
typedef __attribute__((ext_vector_type(4))) float  f32x4;

#define N_IMG 3136   // 56*56
#define NB16  196    // 3136/16
#define CB8   56     // 448/8
#define P_CNT 2496   // 52*48 interior pixels
#define NDIR  34     // stencil directions

// stencil offsets dy*56+dx for RADIUS=5 (matches get_indices_of_pairs order)
__constant__ int c_offs[NDIR] = {
  1,2,3,4,
  52,53,54,55,56,57,58,59,60,
  108,109,110,111,112,113,114,115,116,
  165,166,167,168,169,170,171,
  222,223,224,225,226};

__device__ __forceinline__ void block_sync(){
  // raw barrier: LDS drained, vector-mem loads stay in flight across it
  asm volatile("s_waitcnt lgkmcnt(0)\n\ts_barrier" ::: "memory");
}

__device__ __forceinline__ float elu_f(float v){
  return v > 0.f ? v : expm1f(v);
}

// ---------------- weight f32->bf16 prep (one launch, 4 segments) -------------
__global__ __launch_bounds__(256) void cvt_weights(
    const float* __restrict__ w83, const float* __restrict__ w84,
    const float* __restrict__ w85, const float* __restrict__ w9,
    __bf16* __restrict__ o83, __bf16* __restrict__ o84,
    __bf16* __restrict__ o85, __bf16* __restrict__ o9)
{
  int i = blockIdx.x*256 + threadIdx.x;  // index in float4 units
  const float* src; __bf16* dst; int off;
  if      (i <   8192){ src=w83; dst=o83; off=i; }
  else if (i <  40960){ src=w84; dst=o84; off=i-8192; }
  else if (i < 303104){ src=w85; dst=o85; off=i-40960; }
  else if (i < 353280){ src=w9 ; dst=o9 ; off=i-303104; }
  else return;
  f32x4 v = ((const f32x4*)src)[off];
  bf16x4 o;
  o[0]=(__bf16)v[0]; o[1]=(__bf16)v[1]; o[2]=(__bf16)v[2]; o[3]=(__bf16)v[3];
  ((bf16x4*)dst)[off] = o;
}

// ---------------- fused feature GEMMs -----------------------------------------
// Uniform SMALL tiles: MT=64, NT=64, WG=256 (4 waves, MI=1) -> 1372 blocks,
// ~5.4 blocks/CU, 3+ co-resident (LDS 16KB, VGPR<=128).  Cross-block TLP hides
// the barrier/latency stalls that in-block pipelining could not (R4-R10: every
// schedule variant stuck at ~4800 cyc/step with 1 lockstep block/CU).
//   blocks [0,784)     : conv6 * w85 (4 m-tiles x 49 n x 4 b), K=4096
//   blocks [784,1176)  : conv5 * w84 (2 m-tiles), K=1024
//   blocks [1176,1372) : conv4 * w83 (1 m-tile),  K=512
// All prefetch loads are UNCONDITIONAL with clamped tile index (conditional
// loads defeat the compiler's counted-vmcnt; clamped re-reads are harmless).
// B staged via registers into dbuf LDS, ONE barrier per phase.
// LDS layout: granule (8k) of row n at  n*64 + ((g ^ f(n))<<3),
//   f(n) = ((n ^ (n>>2)) & 7)  -> write-side 2-way (free), read-side even
//   across all 32 banks (conflict-free) — verified by bank arithmetic.
// Output in MFMA-B-fragment layout: idx=(((b*196+n/16)*56+c/8)*16+n%16)*8+c%8
template<int KTOT>
__device__ __forceinline__ void feat_body(
    const float* __restrict__ Xb,      // X + b*KTOT*N_IMG
    const __bf16* __restrict__ Wrow,   // W + m0*KTOT
    __bf16* __restrict__ y1, int c_base /* c_off+m0 */, int b, int n0,
    __bf16 (*Blds)[64*64])
{
  constexpr int NSTEP = KTOT/64;
  static_assert(NSTEP % 2 == 0, "");

  const int tid  = threadIdx.x;        // 0..255
  const int lane = tid & 63;
  const int wm   = tid >> 6;           // 0..3
  const int l15  = lane & 15;
  const int l4   = lane >> 4;
  const int kg   = tid >> 4;           // 0..15 (4 k-rows each)
  const int ng   = tid & 15;           // 0..15 (4 n-cols each)

  float b0[16], b1[16];                // 2-deep B ring (4 f32x4 per set)
  bf16x8 a0[2], a1[2];                 // 2-deep A ring (MI=1: 2 frags per set)
  f32x4 acc[4];
  const f32x4 fz = {0.f,0.f,0.f,0.f};
  #pragma unroll
  for (int ni=0; ni<4; ++ni) acc[ni] = fz;

#define CLAMP(t) ((t) < NSTEP ? (t) : NSTEP-1)

#define LOADA(ar, t) { \
  const int _t = CLAMP(t); \
  _Pragma("unroll") \
  for (int _kk=0;_kk<2;++_kk) \
    (ar)[_kk] = *(const bf16x8*)(Wrow + (size_t)(wm*16 + l15)*KTOT + _t*64 + _kk*32 + l4*8); \
  }

#define LOADB(arr, t) { \
  const int _t = CLAMP(t); \
  const float* _src = Xb + (size_t)(_t*64 + kg*4)*N_IMG + n0 + ng*4; \
  _Pragma("unroll") \
  for (int _j=0;_j<4;++_j){ \
    f32x4 _v = *(const f32x4*)(_src + (size_t)_j*N_IMG); \
    (arr)[_j*4+0]=_v[0]; (arr)[_j*4+1]=_v[1]; (arr)[_j*4+2]=_v[2]; (arr)[_j*4+3]=_v[3]; \
  } }

#define STOREB(arr, bsel) { \
  const int _g = kg >> 1, _h = kg & 1; \
  _Pragma("unroll") \
  for (int _jn=0;_jn<4;++_jn){ \
    const int _n = ng*4 + _jn; \
    const int _f = (_n ^ (_n >> 2)) & 7; \
    bf16x4 _v; \
    _Pragma("unroll") \
    for (int _j=0;_j<4;++_j) _v[_j] = (__bf16)(arr)[_j*4 + _jn]; \
    *(bf16x4*)&Blds[bsel][_n*64 + ((_g ^ _f)<<3) + _h*4] = _v; \
  } }

#define MFMAS(ar, bsel) { \
  _Pragma("unroll") \
  for (int _kk=0;_kk<2;++_kk) \
    _Pragma("unroll") \
    for (int _ni=0;_ni<4;++_ni){ \
      const int _n = _ni*16 + l15; \
      const int _f = (_n ^ (_n >> 2)) & 7; \
      bf16x8 _bv = *(const bf16x8*)&Blds[bsel][_n*64 + (((_kk*4 + l4) ^ _f)<<3)]; \
      acc[_ni] = __builtin_amdgcn_mfma_f32_16x16x32_bf16((ar)[_kk], _bv, acc[_ni], 0,0,0); \
    } }

  // prologue: 2 B tiles + 2 A steps in flight
  LOADB(b0, 0);
  LOADB(b1, 1);
  LOADA(a0, 0);
  LOADA(a1, 1);
  for (int s=0; s<NSTEP; s+=2){
    // phase 0: tile s via buf0
    STOREB(b0, 0);                     // counted-vmcnt wait on b0 only
    LOADB(b0, s+2);                    // unconditional (clamped) refill
    block_sync();
    MFMAS(a0, 0);
    LOADA(a0, s+2);                    // load-after-use (R8 lesson)
    // phase 1: tile s+1 via buf1
    STOREB(b1, 1);
    LOADB(b1, s+3);
    block_sync();
    MFMAS(a1, 1);
    LOADA(a1, s+3);
  }
#undef CLAMP
#undef LOADA
#undef LOADB
#undef STOREB
#undef MFMAS

  // ---- epilogue: elu + store to fragment layout ----
  const int c0 = c_base + wm*16 + l4*4;   // 4 consecutive channels
  const int cb = c0 >> 3;
  const int jj = c0 & 7;
  #pragma unroll
  for (int ni=0; ni<4; ++ni){
    const int n = n0 + ni*16 + l15;
    size_t idx = ((((size_t)b*NB16 + (n>>4))*CB8 + cb)*16 + (n&15))*8 + jj;
    f32x4 a = acc[ni];
    bf16x4 o;
    #pragma unroll
    for (int r=0;r<4;++r) o[r] = (__bf16)elu_f(a[r]);
    *(bf16x4*)(y1 + idx) = o;
  }
}

__global__ __launch_bounds__(256, 4) void gemm_feat_fused(
    const float* __restrict__ conv4, const float* __restrict__ conv5,
    const float* __restrict__ conv6,
    const __bf16* __restrict__ w83b, const __bf16* __restrict__ w84b,
    const __bf16* __restrict__ w85b, __bf16* __restrict__ y1)
{
  __shared__ __bf16 Blds[2][64*64];    // 16 KB dbuf
  const int gid = blockIdx.x;
  if (gid < 784){
    const int mt = gid/196, r = gid%196, b = r/49, nt = r%49;
    feat_body<4096>(conv6 + (size_t)b*4096*N_IMG, w85b + (size_t)mt*64*4096,
                    y1, 192 + mt*64, b, nt*64, Blds);
  } else if (gid < 1176){
    const int g = gid-784, mt = g/196, r = g%196, b = r/49, nt = r%49;
    feat_body<1024>(conv5 + (size_t)b*1024*N_IMG, w84b + (size_t)mt*64*1024,
                    y1, 64 + mt*64, b, nt*64, Blds);
  } else {
    const int g = gid-1176, b = g/49, nt = g%49;
    feat_body<512>(conv4 + (size_t)b*512*N_IMG, w83b,
                   y1, 0, b, nt*64, Blds);
  }
}

// ---------------- output GEMM: x2[n, o] = elu(w9[448x448] * y1) -------------
// LDS-free, barrier-free: both operands frag-loaded direct (L2/L3-resident).
__global__ __launch_bounds__(256) void gemm_out(
    const __bf16* __restrict__ y1, const __bf16* __restrict__ w9b,
    __bf16* __restrict__ x2)
{
  const int nt = blockIdx.x, mt = blockIdx.y, b = blockIdx.z;
  const int tid = threadIdx.x;
  if (mt == 7){
    // zero the pad columns 448..511 of this n-tile
    const int row = tid >> 2, q = tid & 3;
    __bf16* p = x2 + ((size_t)b*N_IMG + nt*64 + row)*512 + 448 + q*16;
    uint4 z = {0u,0u,0u,0u};
    *(uint4*)p = z;
    *(uint4*)(p+8) = z;
    return;
  }
  const int lane = tid & 63, wid = tid >> 6;
  const int l15 = lane & 15, l4 = lane >> 4;
  // each wave owns one 16-col block of y1's fragment layout
  const __bf16* Bbase = y1 + ((size_t)b*NB16 + nt*4 + wid)*CB8*128;
  const __bf16* Abase = w9b + (size_t)(mt*64 + l15)*448 + l4*8;
  f32x4 acc[4];
  const f32x4 fz = {0.f,0.f,0.f,0.f};
  #pragma unroll
  for (int mi=0;mi<4;++mi) acc[mi] = fz;

  for (int s=0;s<7;++s){
    #pragma unroll
    for (int kk=0;kk<2;++kk){
      bf16x8 bv = *(const bf16x8*)(Bbase + (s*2+kk)*512 + lane*8);  // linear lane*16B
      #pragma unroll
      for (int mi=0;mi<4;++mi){
        bf16x8 av = *(const bf16x8*)(Abase + (size_t)mi*16*448 + s*64 + kk*32);
        acc[mi] = __builtin_amdgcn_mfma_f32_16x16x32_bf16(av, bv, acc[mi], 0,0,0);
      }
    }
  }
  #pragma unroll
  for (int mi=0;mi<4;++mi){
    const int o = mt*64 + mi*16 + l4*4;
    const int n = nt*64 + wid*16 + l15;
    f32x4 a = acc[mi];
    bf16x4 v;
    #pragma unroll
    for (int r=0;r<4;++r) v[r] = (__bf16)elu_f(a[r]);
    *(bf16x4*)(x2 + ((size_t)b*N_IMG + n)*512 + o) = v;
  }
}

// ---------------- affinity stencil: one wave per (b, p) ---------------------
__global__ __launch_bounds__(256) void affinity_kernel(
    const __bf16* __restrict__ x2, float* __restrict__ out)
{
  const int b = blockIdx.x;                 // b fastest -> each XCD sees one batch
  const int lane = threadIdx.x & 63, wid = threadIdx.x >> 6;
  const int p = blockIdx.y*4 + wid;
  const int from = (p/48)*56 + 4 + (p%48);
  const __bf16* xb = x2 + (size_t)b*N_IMG*512;
  bf16x8 ffv = *(const bf16x8*)(xb + (size_t)from*512 + lane*8);
  float ff[8];
  #pragma unroll
  for (int j=0;j<8;++j) ff[j] = (float)ffv[j];
  for (int d=0; d<NDIR; ++d){
    const int to = from + c_offs[d];
    bf16x8 ftv = *(const bf16x8*)(xb + (size_t)to*512 + lane*8);
    float s = 0.f;
    #pragma unroll
    for (int j=0;j<8;++j) s += fabsf(ff[j] - (float)ftv[j]);
    #pragma unroll
    for (int m=1;m<64;m<<=1) s += __shfl_xor(s, m, 64);
    if (lane == 0) out[((size_t)b*NDIR + d)*P_CNT + p] = expf(-s*(1.f/448.f));
  }
}

extern "C" void kernel_launch(void* const* d_in, const int* in_sizes, int n_in,
                              void* d_out, int out_size, void* d_ws, size_t ws_size,
                              hipStream_t stream)
{
  (void)in_sizes; (void)n_in; (void)out_size; (void)ws_size;
  const float* conv4 = (const float*)d_in[0];
  const float* conv5 = (const float*)d_in[1];
  const float* conv6 = (const float*)d_in[2];
  const float* w83   = (const float*)d_in[3];
  const float* w84   = (const float*)d_in[4];
  const float* w85   = (const float*)d_in[5];
  const float* w9    = (const float*)d_in[6];
  // ind_from / ind_to (d_in[7], d_in[8]) are recomputed on device (hardcoded stencil)
  float* out = (float*)d_out;
  char* ws = (char*)d_ws;
  // workspace layout (26,910,720 bytes)
  __bf16* w83b = (__bf16*)(ws + 0);         //  64x512
  __bf16* w84b = (__bf16*)(ws + 65536);     // 128x1024
  __bf16* w85b = (__bf16*)(ws + 327680);    // 256x4096
  __bf16* w9b  = (__bf16*)(ws + 2424832);   // 448x448
  __bf16* y1   = (__bf16*)(ws + 2826240);   // 4*3136*448, fragment layout
  __bf16* x2   = (__bf16*)(ws + 14065664);  // 4*3136*512 (448 + zero pad)

  cvt_weights<<<1380, 256, 0, stream>>>(w83,w84,w85,w9, w83b,w84b,w85b,w9b);
  // fused: [0,784)=conv6 (4 m-tiles), [784,1176)=conv5 (2), [1176,1372)=conv4 (1)
  gemm_feat_fused<<<1372, 256, 0, stream>>>(conv4, conv5, conv6, w83b, w84b, w85b, y1);
  gemm_out<<<dim3(49,8,4), 256, 0, stream>>>(y1, w9b, x2);
  affinity_kernel<<<dim3(4,624), 256, 0, stream>>>(x2, out);
}

// Round 12
// 217.214 us; speedup vs baseline: 1.6497x; 1.1223x over previous
//
#include <hip/hip_runtime.h>
#include <hip/hip_bf16.h>
#include <cstdint>

typedef __attribute__((ext_vector_type(8))) __bf16 bf16x8;
typedef __attribute__((ext_vector_type(4))) __bf16 bf16x4;
typedef __attribute__((ext_vector_type(4))) float  f32x4;

#define N_IMG 3136   // 56*56
#define NB16  196    // 3136/16
#define CB8   56     // 448/8
#define P_CNT 2496   // 52*48 interior pixels
#define NDIR  34     // stencil directions

// stencil offsets dy*56+dx for RADIUS=5 (matches get_indices_of_pairs order)
__constant__ int c_offs[NDIR] = {
  1,2,3,4,
  52,53,54,55,56,57,58,59,60,
  108,109,110,111,112,113,114,115,116,
  165,166,167,168,169,170,171,
  222,223,224,225,226};

__device__ __forceinline__ void block_sync(){
  // raw barrier: LDS drained, vector-mem loads stay in flight across it
  asm volatile("s_waitcnt lgkmcnt(0)\n\ts_barrier" ::: "memory");
}

__device__ __forceinline__ float elu_f(float v){
  return v > 0.f ? v : expm1f(v);
}

// ---------------- weight f32->bf16 prep (one launch, 4 segments) -------------
__global__ __launch_bounds__(256) void cvt_weights(
    const float* __restrict__ w83, const float* __restrict__ w84,
    const float* __restrict__ w85, const float* __restrict__ w9,
    __bf16* __restrict__ o83, __bf16* __restrict__ o84,
    __bf16* __restrict__ o85, __bf16* __restrict__ o9)
{
  int i = blockIdx.x*256 + threadIdx.x;  // index in float4 units
  const float* src; __bf16* dst; int off;
  if      (i <   8192){ src=w83; dst=o83; off=i; }
  else if (i <  40960){ src=w84; dst=o84; off=i-8192; }
  else if (i < 303104){ src=w85; dst=o85; off=i-40960; }
  else if (i < 353280){ src=w9 ; dst=o9 ; off=i-303104; }
  else return;
  f32x4 v = ((const f32x4*)src)[off];
  bf16x4 o;
  o[0]=(__bf16)v[0]; o[1]=(__bf16)v[1]; o[2]=(__bf16)v[2]; o[3]=(__bf16)v[3];
  ((bf16x4*)dst)[off] = o;
}

// ---------------- fused feature GEMMs -----------------------------------------
// Uniform SMALL tiles: MT=64, NT=64, WG=256 (4 waves, MI=1).  R11 proved this
// shape delivers 2.9 TB/s DRAM but tripled FETCH (X panels re-read by the 4
// mt-blocks from DIFFERENT XCDs).  R12: XCD CO-LOCATION — the mt-blocks that
// share an X panel get gids equal mod 8 (round-robin gid->XCD), so re-reads
// hit that XCD's 4MB L2:
//   conv6: gid in [0,800):    q=gid>>5, r=gid&31, mt=r>>3, x=r&7, pair=q*8+x
//   conv5: gid in [800,1200): q=(gid-800)>>4, r&15: mt=r>>3, x=r&7, pair=q*8+x
//   conv4: gid in [1200,1396): pair = gid-1200  (no sharing)
//   pair = b*49 + nt;  guard pair>=196 (24 idle blocks).
// All prefetch loads UNCONDITIONAL with clamped tile index; B staged via
// registers into dbuf LDS, ONE barrier per phase; A 2 sets, load-after-use.
// LDS swizzle f(n)=((n^(n>>2))&7): write 2-way (free), read conflict-free.
// Output in MFMA-B-fragment layout: idx=(((b*196+n/16)*56+c/8)*16+n%16)*8+c%8
template<int KTOT>
__device__ __forceinline__ void feat_body(
    const float* __restrict__ Xb,      // X + b*KTOT*N_IMG
    const __bf16* __restrict__ Wrow,   // W + m0*KTOT
    __bf16* __restrict__ y1, int c_base /* c_off+m0 */, int b, int n0,
    __bf16 (*Blds)[64*64])
{
  constexpr int NSTEP = KTOT/64;
  static_assert(NSTEP % 2 == 0, "");

  const int tid  = threadIdx.x;        // 0..255
  const int lane = tid & 63;
  const int wm   = tid >> 6;           // 0..3
  const int l15  = lane & 15;
  const int l4   = lane >> 4;
  const int kg   = tid >> 4;           // 0..15 (4 k-rows each)
  const int ng   = tid & 15;           // 0..15 (4 n-cols each)

  float b0[16], b1[16];                // 2-deep B ring (4 f32x4 per set)
  bf16x8 a0[2], a1[2];                 // 2-deep A ring (MI=1: 2 frags per set)
  f32x4 acc[4];
  const f32x4 fz = {0.f,0.f,0.f,0.f};
  #pragma unroll
  for (int ni=0; ni<4; ++ni) acc[ni] = fz;

#define CLAMP(t) ((t) < NSTEP ? (t) : NSTEP-1)

#define LOADA(ar, t) { \
  const int _t = CLAMP(t); \
  _Pragma("unroll") \
  for (int _kk=0;_kk<2;++_kk) \
    (ar)[_kk] = *(const bf16x8*)(Wrow + (size_t)(wm*16 + l15)*KTOT + _t*64 + _kk*32 + l4*8); \
  }

#define LOADB(arr, t) { \
  const int _t = CLAMP(t); \
  const float* _src = Xb + (size_t)(_t*64 + kg*4)*N_IMG + n0 + ng*4; \
  _Pragma("unroll") \
  for (int _j=0;_j<4;++_j){ \
    f32x4 _v = *(const f32x4*)(_src + (size_t)_j*N_IMG); \
    (arr)[_j*4+0]=_v[0]; (arr)[_j*4+1]=_v[1]; (arr)[_j*4+2]=_v[2]; (arr)[_j*4+3]=_v[3]; \
  } }

#define STOREB(arr, bsel) { \
  const int _g = kg >> 1, _h = kg & 1; \
  _Pragma("unroll") \
  for (int _jn=0;_jn<4;++_jn){ \
    const int _n = ng*4 + _jn; \
    const int _f = (_n ^ (_n >> 2)) & 7; \
    bf16x4 _v; \
    _Pragma("unroll") \
    for (int _j=0;_j<4;++_j) _v[_j] = (__bf16)(arr)[_j*4 + _jn]; \
    *(bf16x4*)&Blds[bsel][_n*64 + ((_g ^ _f)<<3) + _h*4] = _v; \
  } }

#define MFMAS(ar, bsel) { \
  _Pragma("unroll") \
  for (int _kk=0;_kk<2;++_kk) \
    _Pragma("unroll") \
    for (int _ni=0;_ni<4;++_ni){ \
      const int _n = _ni*16 + l15; \
      const int _f = (_n ^ (_n >> 2)) & 7; \
      bf16x8 _bv = *(const bf16x8*)&Blds[bsel][_n*64 + (((_kk*4 + l4) ^ _f)<<3)]; \
      acc[_ni] = __builtin_amdgcn_mfma_f32_16x16x32_bf16((ar)[_kk], _bv, acc[_ni], 0,0,0); \
    } }

  // prologue: 2 B tiles + 2 A steps in flight
  LOADB(b0, 0);
  LOADB(b1, 1);
  LOADA(a0, 0);
  LOADA(a1, 1);
  for (int s=0; s<NSTEP; s+=2){
    // phase 0: tile s via buf0
    STOREB(b0, 0);                     // counted-vmcnt wait on b0 only
    LOADB(b0, s+2);                    // unconditional (clamped) refill
    block_sync();
    MFMAS(a0, 0);
    LOADA(a0, s+2);                    // load-after-use (R8 lesson)
    // phase 1: tile s+1 via buf1
    STOREB(b1, 1);
    LOADB(b1, s+3);
    block_sync();
    MFMAS(a1, 1);
    LOADA(a1, s+3);
  }
#undef CLAMP
#undef LOADA
#undef LOADB
#undef STOREB
#undef MFMAS

  // ---- epilogue: elu + store to fragment layout ----
  const int c0 = c_base + wm*16 + l4*4;   // 4 consecutive channels
  const int cb = c0 >> 3;
  const int jj = c0 & 7;
  #pragma unroll
  for (int ni=0; ni<4; ++ni){
    const int n = n0 + ni*16 + l15;
    size_t idx = ((((size_t)b*NB16 + (n>>4))*CB8 + cb)*16 + (n&15))*8 + jj;
    f32x4 a = acc[ni];
    bf16x4 o;
    #pragma unroll
    for (int r=0;r<4;++r) o[r] = (__bf16)elu_f(a[r]);
    *(bf16x4*)(y1 + idx) = o;
  }
}

__global__ __launch_bounds__(256, 4) void gemm_feat_fused(
    const float* __restrict__ conv4, const float* __restrict__ conv5,
    const float* __restrict__ conv6,
    const __bf16* __restrict__ w83b, const __bf16* __restrict__ w84b,
    const __bf16* __restrict__ w85b, __bf16* __restrict__ y1)
{
  __shared__ __bf16 Blds[2][64*64];    // 16 KB dbuf
  const int gid = blockIdx.x;
  if (gid < 800){
    // conv6: 4 mt-blocks of each pair co-located on one XCD (gids = x mod 8)
    const int q = gid >> 5, r = gid & 31, mt = r >> 3, x = r & 7;
    const int pair = q*8 + x;
    if (pair >= 196) return;
    const int b = pair/49, nt = pair%49;
    feat_body<4096>(conv6 + (size_t)b*4096*N_IMG, w85b + (size_t)mt*64*4096,
                    y1, 192 + mt*64, b, nt*64, Blds);
  } else if (gid < 1200){
    // conv5: 2 mt-blocks of each pair co-located
    const int g = gid-800, q = g >> 4, r = g & 15, mt = r >> 3, x = r & 7;
    const int pair = q*8 + x;
    if (pair >= 196) return;
    const int b = pair/49, nt = pair%49;
    feat_body<1024>(conv5 + (size_t)b*1024*N_IMG, w84b + (size_t)mt*64*1024,
                    y1, 64 + mt*64, b, nt*64, Blds);
  } else {
    // conv4: no sharing
    const int pair = gid-1200, b = pair/49, nt = pair%49;
    feat_body<512>(conv4 + (size_t)b*512*N_IMG, w83b,
                   y1, 0, b, nt*64, Blds);
  }
}

// ---------------- output GEMM: x2[n, o] = elu(w9[448x448] * y1) -------------
// LDS-free, barrier-free: both operands frag-loaded direct (L2/L3-resident).
__global__ __launch_bounds__(256) void gemm_out(
    const __bf16* __restrict__ y1, const __bf16* __restrict__ w9b,
    __bf16* __restrict__ x2)
{
  const int nt = blockIdx.x, mt = blockIdx.y, b = blockIdx.z;
  const int tid = threadIdx.x;
  if (mt == 7){
    // zero the pad columns 448..511 of this n-tile
    const int row = tid >> 2, q = tid & 3;
    __bf16* p = x2 + ((size_t)b*N_IMG + nt*64 + row)*512 + 448 + q*16;
    uint4 z = {0u,0u,0u,0u};
    *(uint4*)p = z;
    *(uint4*)(p+8) = z;
    return;
  }
  const int lane = tid & 63, wid = tid >> 6;
  const int l15 = lane & 15, l4 = lane >> 4;
  // each wave owns one 16-col block of y1's fragment layout
  const __bf16* Bbase = y1 + ((size_t)b*NB16 + nt*4 + wid)*CB8*128;
  const __bf16* Abase = w9b + (size_t)(mt*64 + l15)*448 + l4*8;
  f32x4 acc[4];
  const f32x4 fz = {0.f,0.f,0.f,0.f};
  #pragma unroll
  for (int mi=0;mi<4;++mi) acc[mi] = fz;

  for (int s=0;s<7;++s){
    #pragma unroll
    for (int kk=0;kk<2;++kk){
      bf16x8 bv = *(const bf16x8*)(Bbase + (s*2+kk)*512 + lane*8);  // linear lane*16B
      #pragma unroll
      for (int mi=0;mi<4;++mi){
        bf16x8 av = *(const bf16x8*)(Abase + (size_t)mi*16*448 + s*64 + kk*32);
        acc[mi] = __builtin_amdgcn_mfma_f32_16x16x32_bf16(av, bv, acc[mi], 0,0,0);
      }
    }
  }
  #pragma unroll
  for (int mi=0;mi<4;++mi){
    const int o = mt*64 + mi*16 + l4*4;
    const int n = nt*64 + wid*16 + l15;
    f32x4 a = acc[mi];
    bf16x4 v;
    #pragma unroll
    for (int r=0;r<4;++r) v[r] = (__bf16)elu_f(a[r]);
    *(bf16x4*)(x2 + ((size_t)b*N_IMG + n)*512 + o) = v;
  }
}

// ---------------- affinity stencil: one wave per (b, p) ---------------------
__global__ __launch_bounds__(256) void affinity_kernel(
    const __bf16* __restrict__ x2, float* __restrict__ out)
{
  const int b = blockIdx.x;                 // b fastest -> each XCD sees one batch
  const int lane = threadIdx.x & 63, wid = threadIdx.x >> 6;
  const int p = blockIdx.y*4 + wid;
  const int from = (p/48)*56 + 4 + (p%48);
  const __bf16* xb = x2 + (size_t)b*N_IMG*512;
  bf16x8 ffv = *(const bf16x8*)(xb + (size_t)from*512 + lane*8);
  float ff[8];
  #pragma unroll
  for (int j=0;j<8;++j) ff[j] = (float)ffv[j];
  for (int d=0; d<NDIR; ++d){
    const int to = from + c_offs[d];
    bf16x8 ftv = *(const bf16x8*)(xb + (size_t)to*512 + lane*8);
    float s = 0.f;
    #pragma unroll
    for (int j=0;j<8;++j) s += fabsf(ff[j] - (float)ftv[j]);
    #pragma unroll
    for (int m=1;m<64;m<<=1) s += __shfl_xor(s, m, 64);
    if (lane == 0) out[((size_t)b*NDIR + d)*P_CNT + p] = expf(-s*(1.f/448.f));
  }
}

extern "C" void kernel_launch(void* const* d_in, const int* in_sizes, int n_in,
                              void* d_out, int out_size, void* d_ws, size_t ws_size,
                              hipStream_t stream)
{
  (void)in_sizes; (void)n_in; (void)out_size; (void)ws_size;
  const float* conv4 = (const float*)d_in[0];
  const float* conv5 = (const float*)d_in[1];
  const float* conv6 = (const float*)d_in[2];
  const float* w83   = (const float*)d_in[3];
  const float* w84   = (const float*)d_in[4];
  const float* w85   = (const float*)d_in[5];
  const float* w9    = (const float*)d_in[6];
  // ind_from / ind_to (d_in[7], d_in[8]) are recomputed on device (hardcoded stencil)
  float* out = (float*)d_out;
  char* ws = (char*)d_ws;
  // workspace layout (26,910,720 bytes)
  __bf16* w83b = (__bf16*)(ws + 0);         //  64x512
  __bf16* w84b = (__bf16*)(ws + 65536);     // 128x1024
  __bf16* w85b = (__bf16*)(ws + 327680);    // 256x4096
  __bf16* w9b  = (__bf16*)(ws + 2424832);   // 448x448
  __bf16* y1   = (__bf16*)(ws + 2826240);   // 4*3136*448, fragment layout
  __bf16* x2   = (__bf16*)(ws + 14065664);  // 4*3136*512 (448 + zero pad)

  cvt_weights<<<1380, 256, 0, stream>>>(w83,w84,w85,w9, w83b,w84b,w85b,w9b);
  // fused, XCD co-located: [0,800)=conv6, [800,1200)=conv5, [1200,1396)=conv4
  gemm_feat_fused<<<1396, 256, 0, stream>>>(conv4, conv5, conv6, w83b, w84b, w85b, y1);
  gemm_out<<<dim3(49,8,4), 256, 0, stream>>>(y1, w9b, x2);
  affinity_kernel<<<dim3(4,624), 256, 0, stream>>>(x2, out);
}